// Round 4
// baseline (643.127 us; speedup 1.0000x reference)
//
#include <hip/hip_runtime.h>
#include <hip/hip_bf16.h>

// GCN: 3x GCNConv(relu) -> mean over layers -> global mean pool -> linear -> softmax
// N=100000, E=3200000, F_IN=128, F_HID=64, F_OUT=10, G=1000.
//
// out[dst] = dinv[dst] * ( sum_{e: row[e]=dst} z[col[e]] + z[dst] ) + b,
// z = (x @ W) * dinv[:,None], dinv = rsqrt(deg_col + 1).
//
// R14: R13's sharded bin_edges regressed (write-amp: WRITE_SIZE 49->111MB).
// This round removes preprocessing WORK instead of rearranging it:
//  - CB path deleted: deg_col via global fire-and-forget atomicAdd(degC) in
//    pass 1 (no LDS, no 6.4MB write, no re-read, no histogram in build_csr).
//  - degR also counted globally -> build_csr skips its dst histogram, scans
//    degR directly; indeg array deleted (aggregate reads degR).
//  - bin_edges back to unsharded counters (R12-proven), grid 512 (2 blocks/CU,
//    LDS now ~2KB).
//  - aggregate/gemm/pool unchanged from R13.

#define ALIGN_UP(x, a) (((x) + (a) - 1) / (a) * (a))
#define NBMAX 256        // max buckets (node id >> 9), supports n <= 131072

__device__ __forceinline__ float bf16_to_f32(unsigned short u) {
    return __uint_as_float(((unsigned)u) << 16);
}
__device__ __forceinline__ float bf16_lo(unsigned u) {
    return __uint_as_float(u << 16);
}
__device__ __forceinline__ float bf16_hi(unsigned u) {
    return __uint_as_float(u & 0xffff0000u);
}
__device__ __forceinline__ unsigned pack_bf16(float a, float b) {
    union { __hip_bfloat16 h; unsigned short u; } ua, ub;
    ua.h = __float2bfloat16(a); ub.h = __float2bfloat16(b);
    return (unsigned)ua.u | ((unsigned)ub.u << 16);
}

// ---------------- Pass A: bin edges into 512-node buckets + global degrees ----
// RB entry = (col<<9)|(row&511). degR/degC counted with fire-and-forget global
// atomics (no return -> no wait).
__global__ __launch_bounds__(1024) void bin_edges(const int* __restrict__ row,
                                                  const int* __restrict__ col, int E, int NB, int bcap,
                                                  int* __restrict__ fillR,
                                                  int* __restrict__ degR, int* __restrict__ degC,
                                                  unsigned int* __restrict__ RB) {
    __shared__ int cR[NBMAX], bR[NBMAX];
    int t = threadIdx.x;
    for (int i = t; i < NB; i += 1024) cR[i] = 0;
    __syncthreads();
    int per = (E + gridDim.x - 1) / gridDim.x;
    int e0 = blockIdx.x * per, e1 = min(E, e0 + per);
    for (int e = e0 + t; e < e1; e += 1024) {
        int r = row[e], c = col[e];
        atomicAdd(&cR[r >> 9], 1);
        atomicAdd(&degR[r], 1);          // global, no return: fire-and-forget
        atomicAdd(&degC[c], 1);
    }
    __syncthreads();
    int stag = (int)((blockIdx.x * 37u) % (unsigned)NB);
    for (int j = t; j < NB; j += 1024) {
        int i = j + stag; if (i >= NB) i -= NB;
        bR[i] = cR[i] ? atomicAdd(&fillR[i], cR[i]) : 0;
        cR[i] = 0;                       // reset for pass 2 (same thread owns i)
    }
    __syncthreads();
    for (int e = e0 + t; e < e1; e += 1024) {   // chunk is L2-hot on re-read
        int r = row[e], c = col[e];
        int br = r >> 9;
        int pR = bR[br] + atomicAdd(&cR[br], 1);
        if (pR < bcap) RB[(size_t)br * bcap + pR] = ((unsigned)c << 9) | ((unsigned)r & 511u);
    }
}

// ---------------- Pass B: per-bucket CSR build (512 dst/bucket) + dinv -------
// Histogram comes free from degR; this kernel only scans + scatters.
__global__ __launch_bounds__(1024) void build_csr_impl(const unsigned int* __restrict__ RB,
                                                       const int* __restrict__ fillR,
                                                       const int* __restrict__ degR,
                                                       const int* __restrict__ degC,
                                                       int* __restrict__ rowptr,
                                                       float* __restrict__ dinv, int* __restrict__ csr,
                                                       int n, int NB, int E, int bcap) {
    __shared__ int start[512], bump[512];
    __shared__ int wsum[8];
    __shared__ int s_base;
    int b = blockIdx.x, t = threadIdx.x;
    int node0 = b << 9;
    int v = node0 + t;                           // valid for t<512

    if (b == 0 && t < 64) csr[E + t] = n;        // pad: unguarded index loads -> zero row

    if (t < 64) {
        int pre = 0;
        for (int j = t; j < b; j += 64) pre += min(fillR[j], bcap);
        #pragma unroll
        for (int off = 32; off; off >>= 1) pre += __shfl_down(pre, off, 64);
        if (t == 0) s_base = pre;
    }
    for (int i = t; i < 512; i += 1024) bump[i] = 0;
    __syncthreads();

    // exclusive scan over the 512 node degrees (threads t<512)
    int my = (t < 512 && v < n) ? degR[v] : 0;
    int lane = t & 63, w = t >> 6;               // w in 0..7 for t<512
    int x = my;
    #pragma unroll
    for (int off = 1; off < 64; off <<= 1) {
        int y = __shfl_up(x, off, 64);
        if (lane >= off) x += y;
    }
    if (t < 512 && lane == 63) wsum[w] = x;
    __syncthreads();
    int base = s_base;
    if (t < 512) {
        int wb = 0;
        #pragma unroll
        for (int i = 0; i < 8; i++) if (i < w) wb += wsum[i];
        int excl = wb + x - my;
        start[t] = excl;
        if (v < n) rowptr[v] = base + excl;
    }
    __syncthreads();
    int m = min(fillR[b], bcap);
    const unsigned int* src = RB + (size_t)b * bcap;
    for (int i = t; i < m; i += 1024) {
        unsigned en = src[i];
        int local = (int)(en & 511u);
        int c = (int)(en >> 9);
        int pos = base + start[local] + atomicAdd(&bump[local], 1);
        if (pos < E) csr[pos] = c;               // hardening: never write OOB
    }
    if (t < 512 && v < n) dinv[v] = rsqrtf((float)(degC[v] + 1));
}

// ---------------- dense: Z(bf16) = (X @ W) * dinv[:,None] ----------------
// Block = 64 nodes x 64 outputs. lane = node; wave w owns outputs [16w,16w+16).
// W rows are wave-uniform -> scalar s_load. Input f32 (conv1) or bf16 (conv2/3).
// Writes rows [v0, min(v0+64, n+1)): row n is the all-zero dummy row used by
// aggregate's branchless tail.
template <int K, bool BIN>
__global__ __launch_bounds__(256) void gemm_scale(const void* __restrict__ Xv,
                                                  const float* __restrict__ W,
                                                  const float* __restrict__ dinv,
                                                  unsigned* __restrict__ Z, int n) {
    constexpr int KP = K + 4;                      // row stride (floats), 16B-aligned
    __shared__ __align__(16) float xs[64 * KP];
    int v0 = blockIdx.x * 64;
    int t = threadIdx.x;

    if (BIN) {
        const unsigned* Xu = (const unsigned*)Xv;  // bf16-packed rows of K/2 uints
        constexpr int C8 = K / 8;                  // uint4 chunks per row
        for (int idx = t; idx < 64 * C8; idx += 256) {
            int i = idx / C8, c = idx % C8;
            int v = v0 + i;
            uint4 u = (v < n) ? ((const uint4*)(Xu + (size_t)v * (K / 2)))[c]
                              : make_uint4(0, 0, 0, 0);
            float4 f0, f1;
            f0.x = bf16_lo(u.x); f0.y = bf16_hi(u.x); f0.z = bf16_lo(u.y); f0.w = bf16_hi(u.y);
            f1.x = bf16_lo(u.z); f1.y = bf16_hi(u.z); f1.z = bf16_lo(u.w); f1.w = bf16_hi(u.w);
            *(float4*)&xs[i * KP + c * 8] = f0;
            *(float4*)&xs[i * KP + c * 8 + 4] = f1;
        }
    } else {
        const float* X = (const float*)Xv;
        constexpr int C4 = K / 4;
        for (int idx = t; idx < 64 * C4; idx += 256) {
            int i = idx / C4, c = idx % C4;
            int v = v0 + i;
            float4 val = (v < n) ? ((const float4*)(X + (size_t)v * K))[c]
                                 : make_float4(0.f, 0.f, 0.f, 0.f);
            *(float4*)&xs[i * KP + c * 4] = val;
        }
    }
    __syncthreads();

    int lane = t & 63;
    int wave = __builtin_amdgcn_readfirstlane(t >> 6);
    int j0 = wave * 16;
    float acc[16];
    #pragma unroll
    for (int jj = 0; jj < 16; jj++) acc[jj] = 0.f;

    const float* xrow = &xs[lane * KP];
    #pragma unroll 2
    for (int k = 0; k < K; k += 4) {
        float4 xv = *(const float4*)&xrow[k];
        #pragma unroll
        for (int kk = 0; kk < 4; kk++) {
            float xk = (&xv.x)[kk];
            const float* wrow = W + (k + kk) * 64 + j0;   // wave-uniform -> s_load
            #pragma unroll
            for (int jj = 0; jj < 16; jj++)
                acc[jj] = fmaf(xk, wrow[jj], acc[jj]);
        }
    }

    float dv = (v0 + lane < n) ? dinv[v0 + lane] : 0.f;
    __syncthreads();
    // transpose via LDS (reuse xs) with rotate swizzle; store coalesced bf16 rows
    unsigned* zs32 = (unsigned*)xs;                // 64 nodes x 32 uints (2 bf16 each)
    #pragma unroll
    for (int p = 0; p < 8; p++) {
        int pl = (j0 >> 1) + p;                    // logical uint column
        int phys = (pl + lane) & 31;
        zs32[lane * 32 + phys] = pack_bf16(acc[2 * p] * dv, acc[2 * p + 1] * dv);
    }
    __syncthreads();
    for (int idx = t; idx < 2048; idx += 256) {
        int i = idx >> 5, c = idx & 31;
        int v = v0 + i;
        if (v <= n) Z[(size_t)v * 32 + c] = zs32[i * 32 + ((c + i) & 31)];  // row n = zeros
    }
}

// ---------------- sparse aggregate + bias + relu (bf16 gather -> bf16 out) ----------------
// One wave per dst node. 8 lanes per edge (dwordx4 = 8 features), one wave
// VMEM instr = 8 edges = 8 x 128B lines. Edge indices loaded directly per group
// (8 lanes share one dword; csr padded with n). Gather addresses are 32-bit
// voffsets off a uniform base (saddr form).
__device__ __forceinline__ void acc8(float a[8], uint4 z) {
    a[0] += bf16_lo(z.x); a[1] += bf16_hi(z.x);
    a[2] += bf16_lo(z.y); a[3] += bf16_hi(z.y);
    a[4] += bf16_lo(z.z); a[5] += bf16_hi(z.z);
    a[6] += bf16_lo(z.w); a[7] += bf16_hi(z.w);
}

__global__ __launch_bounds__(256) void aggregate(const uint4* __restrict__ Z4,
                                                 const int* __restrict__ rowptr,
                                                 const int* __restrict__ indeg,
                                                 const int* __restrict__ csr,
                                                 const float* __restrict__ dinv,
                                                 const float* __restrict__ bias,
                                                 uint4* __restrict__ Xout, int n) {
    int wave = threadIdx.x >> 6;
    int lane = threadIdx.x & 63;
    int v = blockIdx.x * 4 + wave;
    if (v >= n) return;
    int vs = __builtin_amdgcn_readfirstlane(v);
    int eg = lane >> 3;                      // edge slot 0..7
    int fl = lane & 7;                       // feature octet (features 8fl..8fl+7)
    unsigned un = (unsigned)n;               // dummy zero row index (also clamp)
    const char* Zb = (const char*)Z4;
    unsigned fo = (unsigned)(fl << 4);       // feature byte offset within row

    int s = rowptr[vs], c = indeg[vs];       // scalar (vs uniform)

    float a[8];
    {
        uint4 sv = make_uint4(0u, 0u, 0u, 0u);
        if (eg == 0) sv = *(const uint4*)(Zb + (((unsigned)vs << 7) + fo));  // self-loop
        a[0] = bf16_lo(sv.x); a[1] = bf16_hi(sv.x);
        a[2] = bf16_lo(sv.y); a[3] = bf16_hi(sv.y);
        a[4] = bf16_lo(sv.z); a[5] = bf16_hi(sv.z);
        a[6] = bf16_lo(sv.w); a[7] = bf16_hi(sv.w);
    }

    // chunk [0,32): 4 index loads (unguarded, pad-safe) -> 4 gathers in flight,
    // acc skipped per dead group by wave-uniform branch (c scalar).
    {
        unsigned j[4];
        #pragma unroll
        for (int g = 0; g < 4; g++) {
            int e = g * 8 + eg;
            unsigned jr = min((unsigned)csr[s + e], un);
            j[g] = (e < c) ? jr : un;
        }
        uint4 zz[4];
        #pragma unroll
        for (int g = 0; g < 4; g++)
            zz[g] = *(const uint4*)(Zb + ((j[g] << 7) + fo));
        #pragma unroll
        for (int g = 0; g < 4; g++)
            if (g * 8 < c) acc8(a, zz[g]);
    }
    if (c > 32) {   // chunk [32,64): skipped entirely for 54% of nodes
        unsigned j[4];
        #pragma unroll
        for (int g = 0; g < 4; g++) {
            int e = 32 + g * 8 + eg;
            unsigned jr = min((unsigned)csr[s + e], un);
            j[g] = (e < c) ? jr : un;
        }
        uint4 zz[4];
        #pragma unroll
        for (int g = 0; g < 4; g++)
            zz[g] = *(const uint4*)(Zb + ((j[g] << 7) + fo));
        #pragma unroll
        for (int g = 0; g < 4; g++)
            if (32 + g * 8 < c) acc8(a, zz[g]);
    }
    for (int b = 64; b < c; b += 32) {   // rare: degree > 64 (pad keeps reads in-bounds)
        unsigned j[4];
        #pragma unroll
        for (int g = 0; g < 4; g++) {
            int e = b + g * 8 + eg;
            unsigned jr = min((unsigned)csr[s + e], un);
            j[g] = (e < c) ? jr : un;
        }
        uint4 zz[4];
        #pragma unroll
        for (int g = 0; g < 4; g++)
            zz[g] = *(const uint4*)(Zb + ((j[g] << 7) + fo));
        #pragma unroll
        for (int g = 0; g < 4; g++)
            if (b + g * 8 < c) acc8(a, zz[g]);
    }

    // combine the 8 edge slots (lanes fl, fl+8, ..., fl+56)
    #pragma unroll
    for (int k = 0; k < 8; k++) {
        a[k] += __shfl_xor(a[k], 8, 64);
        a[k] += __shfl_xor(a[k], 16, 64);
        a[k] += __shfl_xor(a[k], 32, 64);
    }

    if (eg == 0) {
        float dv = dinv[vs];
        float4 b0 = ((const float4*)bias)[2 * fl];
        float4 b1 = ((const float4*)bias)[2 * fl + 1];
        float r0 = fmaxf(fmaf(a[0], dv, b0.x), 0.f);
        float r1 = fmaxf(fmaf(a[1], dv, b0.y), 0.f);
        float r2 = fmaxf(fmaf(a[2], dv, b0.z), 0.f);
        float r3 = fmaxf(fmaf(a[3], dv, b0.w), 0.f);
        float r4 = fmaxf(fmaf(a[4], dv, b1.x), 0.f);
        float r5 = fmaxf(fmaf(a[5], dv, b1.y), 0.f);
        float r6 = fmaxf(fmaf(a[6], dv, b1.z), 0.f);
        float r7 = fmaxf(fmaf(a[7], dv, b1.w), 0.f);
        Xout[(size_t)vs * 8 + fl] = make_uint4(pack_bf16(r0, r1), pack_bf16(r2, r3),
                                               pack_bf16(r4, r5), pack_bf16(r6, r7));
    }
}

// ---------------- fused pool (block per graph, batch sorted) + linear + softmax ----------------
__device__ __forceinline__ int lbound(const int* a, int n, int key) {
    int lo = 0, hi = n;
    while (lo < hi) { int mid = (lo + hi) >> 1; if (a[mid] < key) lo = mid + 1; else hi = mid; }
    return lo;
}

__global__ __launch_bounds__(256) void pool_head(const unsigned* __restrict__ x1,
                                                 const unsigned* __restrict__ x2,
                                                 const unsigned* __restrict__ x3,
                                                 const int* __restrict__ batch,
                                                 const float* __restrict__ Wl,
                                                 const float* __restrict__ bl,
                                                 float* __restrict__ out, int n) {
    __shared__ int sb[2];
    __shared__ float red[4][64];
    __shared__ float ps[64];
    __shared__ float lg[10];
    int g = blockIdx.x, t = threadIdx.x;
    int wave = t >> 6, lane = t & 63;
    if (t < 2) sb[t] = lbound(batch, n, g + t);
    __syncthreads();
    int s0 = sb[0], s1 = sb[1];
    // packed loads: 2 nodes per wave per iter, each lane reads one uint (2 bf16)
    int half = lane >> 5, col = lane & 31;
    float a0 = 0.f, a1 = 0.f;
    for (int v = s0 + wave * 2 + half; v < s1; v += 8) {
        size_t off = (size_t)v * 32 + col;
        unsigned u1 = x1[off], u2 = x2[off], u3 = x3[off];
        a0 += (bf16_lo(u1) + bf16_lo(u2)) + bf16_lo(u3);
        a1 += (bf16_hi(u1) + bf16_hi(u2)) + bf16_hi(u3);
    }
    a0 += __shfl_xor(a0, 32, 64);
    a1 += __shfl_xor(a1, 32, 64);
    if (half == 0) { red[wave][2 * col] = a0; red[wave][2 * col + 1] = a1; }
    __syncthreads();
    if (t < 64) {
        int c = s1 - s0;
        float denom = 3.0f * (float)(c > 1 ? c : 1);
        ps[t] = (red[0][t] + red[1][t] + red[2][t] + red[3][t]) / denom;
    }
    __syncthreads();
    if (t < 10) {
        float a = bl[t];
        #pragma unroll 8
        for (int f = 0; f < 64; f++) a += ps[f] * Wl[f * 10 + t];
        lg[t] = a;
    }
    __syncthreads();
    if (t < 10) {
        float mx = -1e30f;
        for (int j = 0; j < 10; j++) mx = fmaxf(mx, lg[j]);
        float e = expf(lg[t] - mx);
        float ss = 0.f;
        for (int j = 0; j < 10; j++) ss += expf(lg[j] - mx);
        out[g * 10 + t] = e / ss;
    }
}

extern "C" void kernel_launch(void* const* d_in, const int* in_sizes, int n_in,
                              void* d_out, int out_size, void* d_ws, size_t ws_size,
                              hipStream_t stream) {
    const float* feats = (const float*)d_in[0];
    const int*   eidx  = (const int*)d_in[1];
    const int*   batch = (const int*)d_in[2];
    const float* W1 = (const float*)d_in[4];
    const float* b1 = (const float*)d_in[5];
    const float* W2 = (const float*)d_in[6];
    const float* b2 = (const float*)d_in[7];
    const float* W3 = (const float*)d_in[8];
    const float* b3 = (const float*)d_in[9];
    const float* Wl = (const float*)d_in[10];
    const float* bl = (const float*)d_in[11];
    float* out = (float*)d_out;

    int n = in_sizes[0] / 128;
    int E = in_sizes[1] / 2;
    int G = out_size / 10;
    int NB = ((n - 1) >> 9) + 1;                   // 512-node buckets
    int per = E / NB;
    int bcap = ALIGN_UP(per + per / 8 + 512, 64);  // mean + >15 sigma margin
    const int* row = eidx;       // destination
    const int* col = eidx + E;   // source

    char* ws = (char*)d_ws;
    size_t o = 0;
    size_t o_fill   = o; o += ALIGN_UP(NBMAX * 4, 256);              // fillR (zeroed)
    size_t o_degR   = o; o += ALIGN_UP((size_t)n * 4, 256);          // zeroed
    size_t o_degC   = o; o += ALIGN_UP((size_t)n * 4, 256);          // zeroed
    size_t o_rowptr = o; o += ALIGN_UP((size_t)n * 4, 256);
    size_t o_dinv   = o; o += ALIGN_UP((size_t)n * 4, 256);
    size_t o_csr    = o; o += ALIGN_UP((size_t)(E + 64) * 4, 256);   // +64 pad entries = n
    size_t o_z      = o; o += ALIGN_UP(((size_t)n + 1) * 64 * 2, 256); // bf16 Z (+dummy row n)
    size_t o_union  = o;                                             // RB | x1..x3
    size_t rb_bytes = ALIGN_UP((size_t)NB * bcap * 4, 256);
    size_t xl_bytes = ALIGN_UP((size_t)n * 64 * 2, 256);             // bf16 x-layers
    (void)ws_size; (void)n_in; (void)rb_bytes;

    int*   fillR = (int*)(ws + o_fill);
    int*   degR  = (int*)(ws + o_degR);
    int*   degC  = (int*)(ws + o_degC);
    int*   rowptr = (int*)(ws + o_rowptr);
    float* dinv   = (float*)(ws + o_dinv);
    int*   csr    = (int*)(ws + o_csr);
    unsigned* z   = (unsigned*)(ws + o_z);
    unsigned int* RB = (unsigned int*)(ws + o_union);
    unsigned* x1 = (unsigned*)(ws + o_union);                        // overlays RB
    unsigned* x2 = (unsigned*)(ws + o_union + xl_bytes);
    unsigned* x3 = (unsigned*)(ws + o_union + 2 * xl_bytes);

    // zero fillR + degR + degC in one contiguous memset
    hipMemsetAsync(ws + o_fill, 0, o_degC + ALIGN_UP((size_t)n * 4, 256) - o_fill, stream);

    int gridG = n / 64 + 1;      // gemm: 64 nodes per block; always covers dummy row n
    int gridW = (n + 3) / 4;     // aggregate: one wave per node

    bin_edges<<<512, 1024, 0, stream>>>(row, col, E, NB, bcap, fillR, degR, degC, RB);
    build_csr_impl<<<NB, 1024, 0, stream>>>(RB, fillR, degR, degC,
                                            rowptr, dinv, csr, n, NB, E, bcap);

    // conv1 (RB dead after build_csr; x1 overlays it)
    gemm_scale<128, false><<<gridG, 256, 0, stream>>>(feats, W1, dinv, z, n);
    aggregate<<<gridW, 256, 0, stream>>>((const uint4*)z, rowptr, degR, csr, dinv, b1, (uint4*)x1, n);
    // conv2
    gemm_scale<64, true><<<gridG, 256, 0, stream>>>(x1, W2, dinv, z, n);
    aggregate<<<gridW, 256, 0, stream>>>((const uint4*)z, rowptr, degR, csr, dinv, b2, (uint4*)x2, n);
    // conv3
    gemm_scale<64, true><<<gridG, 256, 0, stream>>>(x2, W3, dinv, z, n);
    aggregate<<<gridW, 256, 0, stream>>>((const uint4*)z, rowptr, degR, csr, dinv, b3, (uint4*)x3, n);

    pool_head<<<G, 256, 0, stream>>>((const unsigned*)x1, (const unsigned*)x2,
                                     (const unsigned*)x3, batch, Wl, bl, out, n);
}

// Round 5
// 452.132 us; speedup vs baseline: 1.4224x; 1.4224x over previous
//
#include <hip/hip_runtime.h>
#include <hip/hip_bf16.h>

// GCN: 3x GCNConv(relu) -> mean over layers -> global mean pool -> linear -> softmax
// N=100000, E=3200000, F_IN=128, F_HID=64, F_OUT=10, G=1000.
//
// out[dst] = dinv[dst] * ( sum_{e: row[e]=dst} z[col[e]] + z[dst] ) + b,
// z = (x @ W) * dinv[:,None], dinv = rsqrt(deg_col + 1).
//
// R15: R14's global-atomic degree counting was a disaster (bin_edges 256us,
// WRITE_SIZE 216MB: random device-scope atomics serialize at the coherence
// point). Full revert to the R12-proven bucket scheme (LDS counters, RB+CB,
// bucket-local histograms in build_csr). One geometry change on top:
// bin_edges 1024x256 (1 block/CU, zero phase overlap) -> 512x512 (2 blocks/CU,
// pass-1/pass-2 of neighbor blocks overlap; RB append runs stay >=128B so no
// R13-style write amplification).
// aggregate keeps the R13 saddr/voffset form (20 VGPR) + csr pad.
// NOTE: rare >64-degree tail reads csr[s+e] only for e<c, plus the +64 pad
// covers the unguarded batched reads of the first two chunks.

#define ALIGN_UP(x, a) (((x) + (a) - 1) / (a) * (a))
#define NBMAX 256        // max buckets (node id >> 9), supports n <= 131072
#define BT    512        // bin_edges block size

__device__ __forceinline__ float bf16_to_f32(unsigned short u) {
    return __uint_as_float(((unsigned)u) << 16);
}
__device__ __forceinline__ float bf16_lo(unsigned u) {
    return __uint_as_float(u << 16);
}
__device__ __forceinline__ float bf16_hi(unsigned u) {
    return __uint_as_float(u & 0xffff0000u);
}
__device__ __forceinline__ unsigned pack_bf16(float a, float b) {
    union { __hip_bfloat16 h; unsigned short u; } ua, ub;
    ua.h = __float2bfloat16(a); ub.h = __float2bfloat16(b);
    return (unsigned)ua.u | ((unsigned)ub.u << 16);
}

// ---------------- Pass A: bin edges into 512-node buckets ----------------
// RB entry = (col<<9)|(row&511); CB entry = ushort col&511.
__global__ __launch_bounds__(BT) void bin_edges(const int* __restrict__ row,
                                                const int* __restrict__ col, int E, int NB, int bcap,
                                                int* __restrict__ fillR, int* __restrict__ fillC,
                                                unsigned int* __restrict__ RB,
                                                unsigned short* __restrict__ CB) {
    __shared__ int cR[NBMAX], cC[NBMAX], bR[NBMAX], bC[NBMAX];
    int t = threadIdx.x;
    for (int i = t; i < NB; i += BT) { cR[i] = 0; cC[i] = 0; }
    __syncthreads();
    int per = (E + gridDim.x - 1) / gridDim.x;
    int e0 = blockIdx.x * per, e1 = min(E, e0 + per);
    for (int e = e0 + t; e < e1; e += BT) {
        atomicAdd(&cR[row[e] >> 9], 1);
        atomicAdd(&cC[col[e] >> 9], 1);
    }
    __syncthreads();
    int stag = (int)((blockIdx.x * 37u) % (unsigned)NB);
    for (int j = t; j < NB; j += BT) {
        int i = j + stag; if (i >= NB) i -= NB;
        bR[i] = cR[i] ? atomicAdd(&fillR[i], cR[i]) : 0;
        bC[i] = cC[i] ? atomicAdd(&fillC[i], cC[i]) : 0;
    }
    __syncthreads();
    for (int i = t; i < NB; i += BT) { cR[i] = 0; cC[i] = 0; }
    __syncthreads();
    for (int e = e0 + t; e < e1; e += BT) {      // chunk is L2-hot on re-read
        int r = row[e], c = col[e];
        int br = r >> 9, bc = c >> 9;
        int pR = bR[br] + atomicAdd(&cR[br], 1);
        if (pR < bcap) RB[(size_t)br * bcap + pR] = ((unsigned)c << 9) | ((unsigned)r & 511u);
        int pC = bC[bc] + atomicAdd(&cC[bc], 1);
        if (pC < bcap) CB[(size_t)bc * bcap + pC] = (unsigned short)(c & 511);
    }
}

// ---------------- Pass B: per-bucket CSR build (512 dst/bucket) + dinv ----------------
__global__ __launch_bounds__(1024) void build_csr_impl(const unsigned int* __restrict__ RB,
                                                       const unsigned short* __restrict__ CB,
                                                       const int* __restrict__ fillR,
                                                       const int* __restrict__ fillC,
                                                       int* __restrict__ rowptr, int* __restrict__ indeg,
                                                       float* __restrict__ dinv, int* __restrict__ csr,
                                                       int n, int NB, int E, int bcap) {
    __shared__ int cnt[512], start[512], bump[512];
    __shared__ int wsum[8];
    __shared__ int s_base;
    int b = blockIdx.x, t = threadIdx.x;
    int node0 = b << 9;

    if (b == 0 && t < 64) csr[E + t] = n;       // pad: unguarded index loads hit zero row

    if (t < 64) {
        int pre = 0;
        for (int j = t; j < b; j += 64) pre += min(fillR[j], bcap);
        #pragma unroll
        for (int off = 32; off; off >>= 1) pre += __shfl_down(pre, off, 64);
        if (t == 0) s_base = pre;
    }
    for (int i = t; i < 512; i += 1024) { cnt[i] = 0; bump[i] = 0; }
    __syncthreads();

    int m = min(fillR[b], bcap);
    const unsigned int* src = RB + (size_t)b * bcap;
    for (int i = t; i < m; i += 1024)
        atomicAdd(&cnt[src[i] & 511u], 1);
    __syncthreads();

    // exclusive scan over 512 counters (threads t<512)
    int my = (t < 512) ? cnt[t] : 0;
    int lane = t & 63, w = t >> 6;              // w in 0..7 for t<512
    int x = my;
    #pragma unroll
    for (int off = 1; off < 64; off <<= 1) {
        int y = __shfl_up(x, off, 64);
        if (lane >= off) x += y;
    }
    if (t < 512 && lane == 63) wsum[w] = x;
    __syncthreads();
    int base = s_base;
    if (t < 512) {
        int wb = 0;
        #pragma unroll
        for (int i = 0; i < 8; i++) if (i < w) wb += wsum[i];
        int excl = wb + x - my;
        start[t] = excl;
        int v = node0 + t;
        if (v < n) { rowptr[v] = base + excl; indeg[v] = my; }
    }
    __syncthreads();
    for (int i = t; i < m; i += 1024) {
        unsigned en = src[i];
        int local = (int)(en & 511u);
        int c = (int)(en >> 9);
        int pos = base + start[local] + atomicAdd(&bump[local], 1);
        if (pos < E) csr[pos] = c;              // hardening: never write OOB
    }
    // col-side histogram -> dinv
    __syncthreads();
    for (int i = t; i < 512; i += 1024) cnt[i] = 0;
    __syncthreads();
    int mc = min(fillC[b], bcap);
    const unsigned short* sc = CB + (size_t)b * bcap;
    for (int i = t; i < mc; i += 1024)
        atomicAdd(&cnt[(int)sc[i] & 511], 1);
    __syncthreads();
    int v = node0 + t;
    if (t < 512 && v < n) dinv[v] = rsqrtf((float)(cnt[t] + 1));
}

// ---------------- dense: Z(bf16) = (X @ W) * dinv[:,None] ----------------
// Block = 64 nodes x 64 outputs. lane = node; wave w owns outputs [16w,16w+16).
// W rows are wave-uniform -> scalar s_load. Input f32 (conv1) or bf16 (conv2/3).
// Writes rows [v0, min(v0+64, n+1)): row n is the all-zero dummy row used by
// aggregate's branchless tail.
template <int K, bool BIN>
__global__ __launch_bounds__(256) void gemm_scale(const void* __restrict__ Xv,
                                                  const float* __restrict__ W,
                                                  const float* __restrict__ dinv,
                                                  unsigned* __restrict__ Z, int n) {
    constexpr int KP = K + 4;                      // row stride (floats), 16B-aligned
    __shared__ __align__(16) float xs[64 * KP];
    int v0 = blockIdx.x * 64;
    int t = threadIdx.x;

    if (BIN) {
        const unsigned* Xu = (const unsigned*)Xv;  // bf16-packed rows of K/2 uints
        constexpr int C8 = K / 8;                  // uint4 chunks per row
        for (int idx = t; idx < 64 * C8; idx += 256) {
            int i = idx / C8, c = idx % C8;
            int v = v0 + i;
            uint4 u = (v < n) ? ((const uint4*)(Xu + (size_t)v * (K / 2)))[c]
                              : make_uint4(0, 0, 0, 0);
            float4 f0, f1;
            f0.x = bf16_lo(u.x); f0.y = bf16_hi(u.x); f0.z = bf16_lo(u.y); f0.w = bf16_hi(u.y);
            f1.x = bf16_lo(u.z); f1.y = bf16_hi(u.z); f1.z = bf16_lo(u.w); f1.w = bf16_hi(u.w);
            *(float4*)&xs[i * KP + c * 8] = f0;
            *(float4*)&xs[i * KP + c * 8 + 4] = f1;
        }
    } else {
        const float* X = (const float*)Xv;
        constexpr int C4 = K / 4;
        for (int idx = t; idx < 64 * C4; idx += 256) {
            int i = idx / C4, c = idx % C4;
            int v = v0 + i;
            float4 val = (v < n) ? ((const float4*)(X + (size_t)v * K))[c]
                                 : make_float4(0.f, 0.f, 0.f, 0.f);
            *(float4*)&xs[i * KP + c * 4] = val;
        }
    }
    __syncthreads();

    int lane = t & 63;
    int wave = __builtin_amdgcn_readfirstlane(t >> 6);
    int j0 = wave * 16;
    float acc[16];
    #pragma unroll
    for (int jj = 0; jj < 16; jj++) acc[jj] = 0.f;

    const float* xrow = &xs[lane * KP];
    #pragma unroll 2
    for (int k = 0; k < K; k += 4) {
        float4 xv = *(const float4*)&xrow[k];
        #pragma unroll
        for (int kk = 0; kk < 4; kk++) {
            float xk = (&xv.x)[kk];
            const float* wrow = W + (k + kk) * 64 + j0;   // wave-uniform -> s_load
            #pragma unroll
            for (int jj = 0; jj < 16; jj++)
                acc[jj] = fmaf(xk, wrow[jj], acc[jj]);
        }
    }

    float dv = (v0 + lane < n) ? dinv[v0 + lane] : 0.f;
    __syncthreads();
    // transpose via LDS (reuse xs) with rotate swizzle; store coalesced bf16 rows
    unsigned* zs32 = (unsigned*)xs;                // 64 nodes x 32 uints (2 bf16 each)
    #pragma unroll
    for (int p = 0; p < 8; p++) {
        int pl = (j0 >> 1) + p;                    // logical uint column
        int phys = (pl + lane) & 31;
        zs32[lane * 32 + phys] = pack_bf16(acc[2 * p] * dv, acc[2 * p + 1] * dv);
    }
    __syncthreads();
    for (int idx = t; idx < 2048; idx += 256) {
        int i = idx >> 5, c = idx & 31;
        int v = v0 + i;
        if (v <= n) Z[(size_t)v * 32 + c] = zs32[i * 32 + ((c + i) & 31)];  // row n = zeros
    }
}

// ---------------- sparse aggregate + bias + relu (bf16 gather -> bf16 out) ----------------
// One wave per dst node. 8 lanes per edge (dwordx4 = 8 features), one wave
// VMEM instr = 8 edges = 8 x 128B lines. Edge indices loaded directly per group
// (8 lanes share one dword; csr padded with n). Gather addresses are 32-bit
// voffsets off a uniform base (saddr form).
__device__ __forceinline__ void acc8(float a[8], uint4 z) {
    a[0] += bf16_lo(z.x); a[1] += bf16_hi(z.x);
    a[2] += bf16_lo(z.y); a[3] += bf16_hi(z.y);
    a[4] += bf16_lo(z.z); a[5] += bf16_hi(z.z);
    a[6] += bf16_lo(z.w); a[7] += bf16_hi(z.w);
}

__global__ __launch_bounds__(256) void aggregate(const uint4* __restrict__ Z4,
                                                 const int* __restrict__ rowptr,
                                                 const int* __restrict__ indeg,
                                                 const int* __restrict__ csr,
                                                 const float* __restrict__ dinv,
                                                 const float* __restrict__ bias,
                                                 uint4* __restrict__ Xout, int n) {
    int wave = threadIdx.x >> 6;
    int lane = threadIdx.x & 63;
    int v = blockIdx.x * 4 + wave;
    if (v >= n) return;
    int vs = __builtin_amdgcn_readfirstlane(v);
    int eg = lane >> 3;                      // edge slot 0..7
    int fl = lane & 7;                       // feature octet (features 8fl..8fl+7)
    unsigned un = (unsigned)n;               // dummy zero row index (also clamp)
    const char* Zb = (const char*)Z4;
    unsigned fo = (unsigned)(fl << 4);       // feature byte offset within row

    int s = rowptr[vs], c = indeg[vs];       // scalar (vs uniform)

    float a[8];
    {
        uint4 sv = make_uint4(0u, 0u, 0u, 0u);
        if (eg == 0) sv = *(const uint4*)(Zb + (((unsigned)vs << 7) + fo));  // self-loop
        a[0] = bf16_lo(sv.x); a[1] = bf16_hi(sv.x);
        a[2] = bf16_lo(sv.y); a[3] = bf16_hi(sv.y);
        a[4] = bf16_lo(sv.z); a[5] = bf16_hi(sv.z);
        a[6] = bf16_lo(sv.w); a[7] = bf16_hi(sv.w);
    }

    // chunk [0,32): 4 index loads (unguarded, pad-safe) -> 4 gathers in flight,
    // acc skipped per dead group by wave-uniform branch (c scalar).
    {
        unsigned j[4];
        #pragma unroll
        for (int g = 0; g < 4; g++) {
            int e = g * 8 + eg;
            unsigned jr = min((unsigned)csr[s + e], un);
            j[g] = (e < c) ? jr : un;
        }
        uint4 zz[4];
        #pragma unroll
        for (int g = 0; g < 4; g++)
            zz[g] = *(const uint4*)(Zb + ((j[g] << 7) + fo));
        #pragma unroll
        for (int g = 0; g < 4; g++)
            if (g * 8 < c) acc8(a, zz[g]);
    }
    if (c > 32) {   // chunk [32,64): skipped entirely for 54% of nodes
        unsigned j[4];
        #pragma unroll
        for (int g = 0; g < 4; g++) {
            int e = 32 + g * 8 + eg;
            unsigned jr = min((unsigned)csr[s + e], un);
            j[g] = (e < c) ? jr : un;
        }
        uint4 zz[4];
        #pragma unroll
        for (int g = 0; g < 4; g++)
            zz[g] = *(const uint4*)(Zb + ((j[g] << 7) + fo));
        #pragma unroll
        for (int g = 0; g < 4; g++)
            if (32 + g * 8 < c) acc8(a, zz[g]);
    }
    for (int b = 64; b < c; b += 32) {   // rare: degree > 64 (csr pad keeps reads safe)
        unsigned j[4];
        #pragma unroll
        for (int g = 0; g < 4; g++) {
            int e = b + g * 8 + eg;
            int er = min(e, c - 1 + 64);             // within padded csr
            unsigned jr = min((unsigned)csr[s + er], un);
            j[g] = (e < c) ? jr : un;
        }
        uint4 zz[4];
        #pragma unroll
        for (int g = 0; g < 4; g++)
            zz[g] = *(const uint4*)(Zb + ((j[g] << 7) + fo));
        #pragma unroll
        for (int g = 0; g < 4; g++)
            if (b + g * 8 < c) acc8(a, zz[g]);
    }

    // combine the 8 edge slots (lanes fl, fl+8, ..., fl+56)
    #pragma unroll
    for (int k = 0; k < 8; k++) {
        a[k] += __shfl_xor(a[k], 8, 64);
        a[k] += __shfl_xor(a[k], 16, 64);
        a[k] += __shfl_xor(a[k], 32, 64);
    }

    if (eg == 0) {
        float dv = dinv[vs];
        float4 b0 = ((const float4*)bias)[2 * fl];
        float4 b1 = ((const float4*)bias)[2 * fl + 1];
        float r0 = fmaxf(fmaf(a[0], dv, b0.x), 0.f);
        float r1 = fmaxf(fmaf(a[1], dv, b0.y), 0.f);
        float r2 = fmaxf(fmaf(a[2], dv, b0.z), 0.f);
        float r3 = fmaxf(fmaf(a[3], dv, b0.w), 0.f);
        float r4 = fmaxf(fmaf(a[4], dv, b1.x), 0.f);
        float r5 = fmaxf(fmaf(a[5], dv, b1.y), 0.f);
        float r6 = fmaxf(fmaf(a[6], dv, b1.z), 0.f);
        float r7 = fmaxf(fmaf(a[7], dv, b1.w), 0.f);
        Xout[(size_t)vs * 8 + fl] = make_uint4(pack_bf16(r0, r1), pack_bf16(r2, r3),
                                               pack_bf16(r4, r5), pack_bf16(r6, r7));
    }
}

// ---------------- fused pool (block per graph, batch sorted) + linear + softmax ----------------
__device__ __forceinline__ int lbound(const int* a, int n, int key) {
    int lo = 0, hi = n;
    while (lo < hi) { int mid = (lo + hi) >> 1; if (a[mid] < key) lo = mid + 1; else hi = mid; }
    return lo;
}

__global__ __launch_bounds__(256) void pool_head(const unsigned* __restrict__ x1,
                                                 const unsigned* __restrict__ x2,
                                                 const unsigned* __restrict__ x3,
                                                 const int* __restrict__ batch,
                                                 const float* __restrict__ Wl,
                                                 const float* __restrict__ bl,
                                                 float* __restrict__ out, int n) {
    __shared__ int sb[2];
    __shared__ float red[4][64];
    __shared__ float ps[64];
    __shared__ float lg[10];
    int g = blockIdx.x, t = threadIdx.x;
    int wave = t >> 6, lane = t & 63;
    if (t < 2) sb[t] = lbound(batch, n, g + t);
    __syncthreads();
    int s0 = sb[0], s1 = sb[1];
    // packed loads: 2 nodes per wave per iter, each lane reads one uint (2 bf16)
    int half = lane >> 5, col = lane & 31;
    float a0 = 0.f, a1 = 0.f;
    for (int v = s0 + wave * 2 + half; v < s1; v += 8) {
        size_t off = (size_t)v * 32 + col;
        unsigned u1 = x1[off], u2 = x2[off], u3 = x3[off];
        a0 += (bf16_lo(u1) + bf16_lo(u2)) + bf16_lo(u3);
        a1 += (bf16_hi(u1) + bf16_hi(u2)) + bf16_hi(u3);
    }
    a0 += __shfl_xor(a0, 32, 64);
    a1 += __shfl_xor(a1, 32, 64);
    if (half == 0) { red[wave][2 * col] = a0; red[wave][2 * col + 1] = a1; }
    __syncthreads();
    if (t < 64) {
        int c = s1 - s0;
        float denom = 3.0f * (float)(c > 1 ? c : 1);
        ps[t] = (red[0][t] + red[1][t] + red[2][t] + red[3][t]) / denom;
    }
    __syncthreads();
    if (t < 10) {
        float a = bl[t];
        #pragma unroll 8
        for (int f = 0; f < 64; f++) a += ps[f] * Wl[f * 10 + t];
        lg[t] = a;
    }
    __syncthreads();
    if (t < 10) {
        float mx = -1e30f;
        for (int j = 0; j < 10; j++) mx = fmaxf(mx, lg[j]);
        float e = expf(lg[t] - mx);
        float ss = 0.f;
        for (int j = 0; j < 10; j++) ss += expf(lg[j] - mx);
        out[g * 10 + t] = e / ss;
    }
}

extern "C" void kernel_launch(void* const* d_in, const int* in_sizes, int n_in,
                              void* d_out, int out_size, void* d_ws, size_t ws_size,
                              hipStream_t stream) {
    const float* feats = (const float*)d_in[0];
    const int*   eidx  = (const int*)d_in[1];
    const int*   batch = (const int*)d_in[2];
    const float* W1 = (const float*)d_in[4];
    const float* b1 = (const float*)d_in[5];
    const float* W2 = (const float*)d_in[6];
    const float* b2 = (const float*)d_in[7];
    const float* W3 = (const float*)d_in[8];
    const float* b3 = (const float*)d_in[9];
    const float* Wl = (const float*)d_in[10];
    const float* bl = (const float*)d_in[11];
    float* out = (float*)d_out;

    int n = in_sizes[0] / 128;
    int E = in_sizes[1] / 2;
    int G = out_size / 10;
    int NB = ((n - 1) >> 9) + 1;                   // 512-node buckets
    int per = E / NB;
    int bcap = ALIGN_UP(per + per / 8 + 512, 64);  // mean + >15 sigma margin
    const int* row = eidx;       // destination
    const int* col = eidx + E;   // source

    char* ws = (char*)d_ws;
    size_t o = 0;
    size_t o_fill   = o; o += 2 * NBMAX * 4;                         // fillR | fillC (zeroed)
    size_t o_rowptr = o; o += ALIGN_UP((size_t)n * 4, 256);
    size_t o_indeg  = o; o += ALIGN_UP((size_t)n * 4, 256);
    size_t o_dinv   = o; o += ALIGN_UP((size_t)n * 4, 256);
    size_t o_csr    = o; o += ALIGN_UP((size_t)(E + 64) * 4, 256);   // +64 pad entries = n
    size_t o_z      = o; o += ALIGN_UP(((size_t)n + 1) * 64 * 2, 256); // bf16 Z (+dummy row n)
    size_t o_union  = o;                                             // RB+CB | x1..x3
    size_t rb_bytes = ALIGN_UP((size_t)NB * bcap * 4, 256);
    size_t xl_bytes = ALIGN_UP((size_t)n * 64 * 2, 256);             // bf16 x-layers
    (void)ws_size; (void)n_in;

    int*   fillR = (int*)(ws + o_fill);
    int*   fillC = fillR + NBMAX;
    int*   rowptr = (int*)(ws + o_rowptr);
    int*   indeg  = (int*)(ws + o_indeg);
    float* dinv   = (float*)(ws + o_dinv);
    int*   csr    = (int*)(ws + o_csr);
    unsigned* z   = (unsigned*)(ws + o_z);
    unsigned int*   RB = (unsigned int*)(ws + o_union);
    unsigned short* CB = (unsigned short*)(ws + o_union + rb_bytes);
    unsigned* x1 = (unsigned*)(ws + o_union);                        // overlays RB/CB
    unsigned* x2 = (unsigned*)(ws + o_union + xl_bytes);
    unsigned* x3 = (unsigned*)(ws + o_union + 2 * xl_bytes);

    hipMemsetAsync(ws + o_fill, 0, 2 * NBMAX * 4, stream);

    int gridG = n / 64 + 1;      // gemm: 64 nodes per block; always covers dummy row n
    int gridW = (n + 3) / 4;     // aggregate: one wave per node

    bin_edges<<<512, BT, 0, stream>>>(row, col, E, NB, bcap, fillR, fillC, RB, CB);
    build_csr_impl<<<NB, 1024, 0, stream>>>(RB, CB, fillR, fillC,
                                            rowptr, indeg, dinv, csr, n, NB, E, bcap);

    // conv1 (RB/CB dead after build_csr; x1 overlays them)
    gemm_scale<128, false><<<gridG, 256, 0, stream>>>(feats, W1, dinv, z, n);
    aggregate<<<gridW, 256, 0, stream>>>((const uint4*)z, rowptr, indeg, csr, dinv, b1, (uint4*)x1, n);
    // conv2
    gemm_scale<64, true><<<gridG, 256, 0, stream>>>(x1, W2, dinv, z, n);
    aggregate<<<gridW, 256, 0, stream>>>((const uint4*)z, rowptr, indeg, csr, dinv, b2, (uint4*)x2, n);
    // conv3
    gemm_scale<64, true><<<gridG, 256, 0, stream>>>(x2, W3, dinv, z, n);
    aggregate<<<gridW, 256, 0, stream>>>((const uint4*)z, rowptr, indeg, csr, dinv, b3, (uint4*)x3, n);

    pool_head<<<G, 256, 0, stream>>>((const unsigned*)x1, (const unsigned*)x2,
                                     (const unsigned*)x3, batch, Wl, bl, out, n);
}

// Round 6
// 422.815 us; speedup vs baseline: 1.5211x; 1.0693x over previous
//
#include <hip/hip_runtime.h>
#include <hip/hip_bf16.h>

// GCN: 3x GCNConv(relu) -> mean over layers -> global mean pool -> linear -> softmax
// N=100000, E=3200000, F_IN=128, F_HID=64, F_OUT=10, G=1000.
//
// out[dst] = dinv[dst] * ( sum_{e: row[e]=dst} z[col[e]] + z[dst] ) + b,
// z = (x @ W) * dinv[:,None], dinv = rsqrt(deg_col + 1).
//
// R16: bin_edges write amplification was the binding term (R15: WRITE_SIZE
// 124MB, 2.4TB/s, 62us; scattered per-bucket appends land partial lines).
// Rewrite as LDS radix-partition: load chunk once into regs (13 edges/thread),
// LDS histogram + parallel 256-entry scans (R: waves 0-3, C: waves 4-7), one
// global atomicAdd per (bucket,block), scatter into LDS-sorted buffer, flush
// coalesced runs (consecutive threads -> consecutive addresses). RB then CB
// sequentially reuse one 50KB buffer; ~55KB LDS, 2 blocks/CU.
// build_csr / gemm / aggregate / pool unchanged from R15.

#define ALIGN_UP(x, a) (((x) + (a) - 1) / (a) * (a))
#define NBMAX 256        // max buckets (node id >> 9), supports n <= 131072
#define CHUNK 12500      // max edges per bin block (13 regs/thread, fits LDS)

__device__ __forceinline__ float bf16_to_f32(unsigned short u) {
    return __uint_as_float(((unsigned)u) << 16);
}
__device__ __forceinline__ float bf16_lo(unsigned u) {
    return __uint_as_float(u << 16);
}
__device__ __forceinline__ float bf16_hi(unsigned u) {
    return __uint_as_float(u & 0xffff0000u);
}
__device__ __forceinline__ unsigned pack_bf16(float a, float b) {
    union { __hip_bfloat16 h; unsigned short u; } ua, ub;
    ua.h = __float2bfloat16(a); ub.h = __float2bfloat16(b);
    return (unsigned)ua.u | ((unsigned)ub.u << 16);
}

// ---------------- Pass A: LDS radix-partition of edges into 512-node buckets ----
// RB entry = (col<<9)|(row&511); CB entry = ushort col&511.
__global__ __launch_bounds__(1024, 8) void bin_edges_sort(const int* __restrict__ row,
                                                          const int* __restrict__ col,
                                                          int E, int NB, int bcap,
                                                          int* __restrict__ fillR,
                                                          int* __restrict__ fillC,
                                                          unsigned int* __restrict__ RB,
                                                          unsigned short* __restrict__ CB) {
    __shared__ unsigned int sortB[CHUNK + 44];     // 50KB; reused as ushort for C
    __shared__ int cntR[NBMAX], cntC[NBMAX];       // histogram, then scatter cursors
    __shared__ int offR[NBMAX + 1], offC[NBMAX + 1];
    __shared__ int baseR[NBMAX], baseC[NBMAX];
    __shared__ int wsumR[4], wsumC[4];

    int t = threadIdx.x;
    for (int i = t; i < NBMAX; i += 1024) { cntR[i] = 0; cntC[i] = 0; }
    __syncthreads();

    int per = (E + gridDim.x - 1) / gridDim.x;     // <= CHUNK by grid sizing
    int e0 = blockIdx.x * per, e1 = min(E, e0 + per);
    int m = e1 - e0;

    // load chunk ONCE into registers (fully unrolled -> static indexing)
    int r[13], c[13];
    #pragma unroll
    for (int k = 0; k < 13; k++) {
        int e = e0 + t + (k << 10);
        bool ok = e < e1;
        r[k] = ok ? row[e] : -1;
        c[k] = ok ? col[e] : 0;
    }
    // histogram
    #pragma unroll
    for (int k = 0; k < 13; k++) {
        if (r[k] >= 0) {
            atomicAdd(&cntR[r[k] >> 9], 1);
            atomicAdd(&cntC[c[k] >> 9], 1);
        }
    }
    __syncthreads();

    // parallel exclusive scans over 256 counters: waves 0-3 -> R, waves 4-7 -> C
    int idx = t & 255;
    bool isR = t < 256, isC = (t >= 256) && (t < 512);
    int val = isR ? cntR[idx] : (isC ? cntC[idx] : 0);
    int lane = t & 63, w4 = (t >> 6) & 3;
    int x = val;
    #pragma unroll
    for (int off = 1; off < 64; off <<= 1) {
        int y = __shfl_up(x, off, 64);
        if (lane >= off) x += y;
    }
    if (isR && lane == 63) wsumR[w4] = x;
    if (isC && lane == 63) wsumC[w4] = x;
    __syncthreads();
    if (isR) {
        int wb = 0;
        #pragma unroll
        for (int i = 0; i < 4; i++) if (i < w4) wb += wsumR[i];
        offR[idx] = wb + x - val;
        if (idx < NB) baseR[idx] = val ? atomicAdd(&fillR[idx], val) : 0;
    }
    if (isC) {
        int wb = 0;
        #pragma unroll
        for (int i = 0; i < 4; i++) if (i < w4) wb += wsumC[i];
        offC[idx] = wb + x - val;
        if (idx < NB) baseC[idx] = val ? atomicAdd(&fillC[idx], val) : 0;
    }
    if (t == 0) offR[NBMAX] = m;
    if (t == 1) offC[NBMAX] = m;
    __syncthreads();
    for (int i = t; i < NBMAX; i += 1024) { cntR[i] = 0; cntC[i] = 0; }  // -> cursors
    __syncthreads();

    // ---- row side: scatter into LDS-sorted order, flush coalesced ----
    #pragma unroll
    for (int k = 0; k < 13; k++) {
        if (r[k] >= 0) {
            int b = r[k] >> 9;
            int p = offR[b] + atomicAdd(&cntR[b], 1);
            sortB[p] = ((unsigned)c[k] << 9) | ((unsigned)r[k] & 511u);
        }
    }
    __syncthreads();
    for (int i = t; i < m; i += 1024) {
        int lo = 0, hi = NB;                       // offR[lo] <= i < offR[hi]
        while (hi - lo > 1) { int mid = (lo + hi) >> 1; if (offR[mid] <= i) lo = mid; else hi = mid; }
        int g = baseR[lo] + (i - offR[lo]);
        if (g < bcap) RB[(size_t)lo * bcap + g] = sortB[i];
    }
    __syncthreads();

    // ---- col side: reuse the buffer as ushort ----
    unsigned short* sortS = (unsigned short*)sortB;
    #pragma unroll
    for (int k = 0; k < 13; k++) {
        if (r[k] >= 0) {
            int b = c[k] >> 9;
            int q = offC[b] + atomicAdd(&cntC[b], 1);
            sortS[q] = (unsigned short)(c[k] & 511);
        }
    }
    __syncthreads();
    for (int i = t; i < m; i += 1024) {
        int lo = 0, hi = NB;
        while (hi - lo > 1) { int mid = (lo + hi) >> 1; if (offC[mid] <= i) lo = mid; else hi = mid; }
        int g = baseC[lo] + (i - offC[lo]);
        if (g < bcap) CB[(size_t)lo * bcap + g] = sortS[i];
    }
}

// ---------------- Pass B: per-bucket CSR build (512 dst/bucket) + dinv ----------------
__global__ __launch_bounds__(1024) void build_csr_impl(const unsigned int* __restrict__ RB,
                                                       const unsigned short* __restrict__ CB,
                                                       const int* __restrict__ fillR,
                                                       const int* __restrict__ fillC,
                                                       int* __restrict__ rowptr, int* __restrict__ indeg,
                                                       float* __restrict__ dinv, int* __restrict__ csr,
                                                       int n, int NB, int E, int bcap) {
    __shared__ int cnt[512], start[512], bump[512];
    __shared__ int wsum[8];
    __shared__ int s_base;
    int b = blockIdx.x, t = threadIdx.x;
    int node0 = b << 9;

    if (b == 0 && t < 64) csr[E + t] = n;       // pad: unguarded index loads hit zero row

    if (t < 64) {
        int pre = 0;
        for (int j = t; j < b; j += 64) pre += min(fillR[j], bcap);
        #pragma unroll
        for (int off = 32; off; off >>= 1) pre += __shfl_down(pre, off, 64);
        if (t == 0) s_base = pre;
    }
    for (int i = t; i < 512; i += 1024) { cnt[i] = 0; bump[i] = 0; }
    __syncthreads();

    int m = min(fillR[b], bcap);
    const unsigned int* src = RB + (size_t)b * bcap;
    for (int i = t; i < m; i += 1024)
        atomicAdd(&cnt[src[i] & 511u], 1);
    __syncthreads();

    // exclusive scan over 512 counters (threads t<512)
    int my = (t < 512) ? cnt[t] : 0;
    int lane = t & 63, w = t >> 6;              // w in 0..7 for t<512
    int x = my;
    #pragma unroll
    for (int off = 1; off < 64; off <<= 1) {
        int y = __shfl_up(x, off, 64);
        if (lane >= off) x += y;
    }
    if (t < 512 && lane == 63) wsum[w] = x;
    __syncthreads();
    int base = s_base;
    if (t < 512) {
        int wb = 0;
        #pragma unroll
        for (int i = 0; i < 8; i++) if (i < w) wb += wsum[i];
        int excl = wb + x - my;
        start[t] = excl;
        int v = node0 + t;
        if (v < n) { rowptr[v] = base + excl; indeg[v] = my; }
    }
    __syncthreads();
    for (int i = t; i < m; i += 1024) {
        unsigned en = src[i];
        int local = (int)(en & 511u);
        int c = (int)(en >> 9);
        int pos = base + start[local] + atomicAdd(&bump[local], 1);
        if (pos < E) csr[pos] = c;              // hardening: never write OOB
    }
    // col-side histogram -> dinv
    __syncthreads();
    for (int i = t; i < 512; i += 1024) cnt[i] = 0;
    __syncthreads();
    int mc = min(fillC[b], bcap);
    const unsigned short* sc = CB + (size_t)b * bcap;
    for (int i = t; i < mc; i += 1024)
        atomicAdd(&cnt[(int)sc[i] & 511], 1);
    __syncthreads();
    int v = node0 + t;
    if (t < 512 && v < n) dinv[v] = rsqrtf((float)(cnt[t] + 1));
}

// ---------------- dense: Z(bf16) = (X @ W) * dinv[:,None] ----------------
// Block = 64 nodes x 64 outputs. lane = node; wave w owns outputs [16w,16w+16).
// W rows are wave-uniform -> scalar s_load. Input f32 (conv1) or bf16 (conv2/3).
// Writes rows [v0, min(v0+64, n+1)): row n is the all-zero dummy row used by
// aggregate's branchless tail.
template <int K, bool BIN>
__global__ __launch_bounds__(256) void gemm_scale(const void* __restrict__ Xv,
                                                  const float* __restrict__ W,
                                                  const float* __restrict__ dinv,
                                                  unsigned* __restrict__ Z, int n) {
    constexpr int KP = K + 4;                      // row stride (floats), 16B-aligned
    __shared__ __align__(16) float xs[64 * KP];
    int v0 = blockIdx.x * 64;
    int t = threadIdx.x;

    if (BIN) {
        const unsigned* Xu = (const unsigned*)Xv;  // bf16-packed rows of K/2 uints
        constexpr int C8 = K / 8;                  // uint4 chunks per row
        for (int idx = t; idx < 64 * C8; idx += 256) {
            int i = idx / C8, c = idx % C8;
            int v = v0 + i;
            uint4 u = (v < n) ? ((const uint4*)(Xu + (size_t)v * (K / 2)))[c]
                              : make_uint4(0, 0, 0, 0);
            float4 f0, f1;
            f0.x = bf16_lo(u.x); f0.y = bf16_hi(u.x); f0.z = bf16_lo(u.y); f0.w = bf16_hi(u.y);
            f1.x = bf16_lo(u.z); f1.y = bf16_hi(u.z); f1.z = bf16_lo(u.w); f1.w = bf16_hi(u.w);
            *(float4*)&xs[i * KP + c * 8] = f0;
            *(float4*)&xs[i * KP + c * 8 + 4] = f1;
        }
    } else {
        const float* X = (const float*)Xv;
        constexpr int C4 = K / 4;
        for (int idx = t; idx < 64 * C4; idx += 256) {
            int i = idx / C4, c = idx % C4;
            int v = v0 + i;
            float4 val = (v < n) ? ((const float4*)(X + (size_t)v * K))[c]
                                 : make_float4(0.f, 0.f, 0.f, 0.f);
            *(float4*)&xs[i * KP + c * 4] = val;
        }
    }
    __syncthreads();

    int lane = t & 63;
    int wave = __builtin_amdgcn_readfirstlane(t >> 6);
    int j0 = wave * 16;
    float acc[16];
    #pragma unroll
    for (int jj = 0; jj < 16; jj++) acc[jj] = 0.f;

    const float* xrow = &xs[lane * KP];
    #pragma unroll 2
    for (int k = 0; k < K; k += 4) {
        float4 xv = *(const float4*)&xrow[k];
        #pragma unroll
        for (int kk = 0; kk < 4; kk++) {
            float xk = (&xv.x)[kk];
            const float* wrow = W + (k + kk) * 64 + j0;   // wave-uniform -> s_load
            #pragma unroll
            for (int jj = 0; jj < 16; jj++)
                acc[jj] = fmaf(xk, wrow[jj], acc[jj]);
        }
    }

    float dv = (v0 + lane < n) ? dinv[v0 + lane] : 0.f;
    __syncthreads();
    // transpose via LDS (reuse xs) with rotate swizzle; store coalesced bf16 rows
    unsigned* zs32 = (unsigned*)xs;                // 64 nodes x 32 uints (2 bf16 each)
    #pragma unroll
    for (int p = 0; p < 8; p++) {
        int pl = (j0 >> 1) + p;                    // logical uint column
        int phys = (pl + lane) & 31;
        zs32[lane * 32 + phys] = pack_bf16(acc[2 * p] * dv, acc[2 * p + 1] * dv);
    }
    __syncthreads();
    for (int idx = t; idx < 2048; idx += 256) {
        int i = idx >> 5, c = idx & 31;
        int v = v0 + i;
        if (v <= n) Z[(size_t)v * 32 + c] = zs32[i * 32 + ((c + i) & 31)];  // row n = zeros
    }
}

// ---------------- sparse aggregate + bias + relu (bf16 gather -> bf16 out) ----------------
// One wave per dst node. 8 lanes per edge (dwordx4 = 8 features), one wave
// VMEM instr = 8 edges = 8 x 128B lines. Edge indices loaded directly per group
// (8 lanes share one dword; csr padded with n). Gather addresses are 32-bit
// voffsets off a uniform base (saddr form).
__device__ __forceinline__ void acc8(float a[8], uint4 z) {
    a[0] += bf16_lo(z.x); a[1] += bf16_hi(z.x);
    a[2] += bf16_lo(z.y); a[3] += bf16_hi(z.y);
    a[4] += bf16_lo(z.z); a[5] += bf16_hi(z.z);
    a[6] += bf16_lo(z.w); a[7] += bf16_hi(z.w);
}

__global__ __launch_bounds__(256) void aggregate(const uint4* __restrict__ Z4,
                                                 const int* __restrict__ rowptr,
                                                 const int* __restrict__ indeg,
                                                 const int* __restrict__ csr,
                                                 const float* __restrict__ dinv,
                                                 const float* __restrict__ bias,
                                                 uint4* __restrict__ Xout, int n) {
    int wave = threadIdx.x >> 6;
    int lane = threadIdx.x & 63;
    int v = blockIdx.x * 4 + wave;
    if (v >= n) return;
    int vs = __builtin_amdgcn_readfirstlane(v);
    int eg = lane >> 3;                      // edge slot 0..7
    int fl = lane & 7;                       // feature octet (features 8fl..8fl+7)
    unsigned un = (unsigned)n;               // dummy zero row index (also clamp)
    const char* Zb = (const char*)Z4;
    unsigned fo = (unsigned)(fl << 4);       // feature byte offset within row

    int s = rowptr[vs], c = indeg[vs];       // scalar (vs uniform)

    float a[8];
    {
        uint4 sv = make_uint4(0u, 0u, 0u, 0u);
        if (eg == 0) sv = *(const uint4*)(Zb + (((unsigned)vs << 7) + fo));  // self-loop
        a[0] = bf16_lo(sv.x); a[1] = bf16_hi(sv.x);
        a[2] = bf16_lo(sv.y); a[3] = bf16_hi(sv.y);
        a[4] = bf16_lo(sv.z); a[5] = bf16_hi(sv.z);
        a[6] = bf16_lo(sv.w); a[7] = bf16_hi(sv.w);
    }

    // chunk [0,32): 4 index loads (unguarded, pad-safe) -> 4 gathers in flight,
    // acc skipped per dead group by wave-uniform branch (c scalar).
    {
        unsigned j[4];
        #pragma unroll
        for (int g = 0; g < 4; g++) {
            int e = g * 8 + eg;
            unsigned jr = min((unsigned)csr[s + e], un);
            j[g] = (e < c) ? jr : un;
        }
        uint4 zz[4];
        #pragma unroll
        for (int g = 0; g < 4; g++)
            zz[g] = *(const uint4*)(Zb + ((j[g] << 7) + fo));
        #pragma unroll
        for (int g = 0; g < 4; g++)
            if (g * 8 < c) acc8(a, zz[g]);
    }
    if (c > 32) {   // chunk [32,64): skipped entirely for 54% of nodes
        unsigned j[4];
        #pragma unroll
        for (int g = 0; g < 4; g++) {
            int e = 32 + g * 8 + eg;
            unsigned jr = min((unsigned)csr[s + e], un);
            j[g] = (e < c) ? jr : un;
        }
        uint4 zz[4];
        #pragma unroll
        for (int g = 0; g < 4; g++)
            zz[g] = *(const uint4*)(Zb + ((j[g] << 7) + fo));
        #pragma unroll
        for (int g = 0; g < 4; g++)
            if (32 + g * 8 < c) acc8(a, zz[g]);
    }
    for (int b = 64; b < c; b += 32) {   // rare: degree > 64 (csr pad keeps reads safe)
        unsigned j[4];
        #pragma unroll
        for (int g = 0; g < 4; g++) {
            int e = b + g * 8 + eg;
            int er = min(e, c - 1 + 64);             // within padded csr
            unsigned jr = min((unsigned)csr[s + er], un);
            j[g] = (e < c) ? jr : un;
        }
        uint4 zz[4];
        #pragma unroll
        for (int g = 0; g < 4; g++)
            zz[g] = *(const uint4*)(Zb + ((j[g] << 7) + fo));
        #pragma unroll
        for (int g = 0; g < 4; g++)
            if (b + g * 8 < c) acc8(a, zz[g]);
    }

    // combine the 8 edge slots (lanes fl, fl+8, ..., fl+56)
    #pragma unroll
    for (int k = 0; k < 8; k++) {
        a[k] += __shfl_xor(a[k], 8, 64);
        a[k] += __shfl_xor(a[k], 16, 64);
        a[k] += __shfl_xor(a[k], 32, 64);
    }

    if (eg == 0) {
        float dv = dinv[vs];
        float4 b0 = ((const float4*)bias)[2 * fl];
        float4 b1 = ((const float4*)bias)[2 * fl + 1];
        float r0 = fmaxf(fmaf(a[0], dv, b0.x), 0.f);
        float r1 = fmaxf(fmaf(a[1], dv, b0.y), 0.f);
        float r2 = fmaxf(fmaf(a[2], dv, b0.z), 0.f);
        float r3 = fmaxf(fmaf(a[3], dv, b0.w), 0.f);
        float r4 = fmaxf(fmaf(a[4], dv, b1.x), 0.f);
        float r5 = fmaxf(fmaf(a[5], dv, b1.y), 0.f);
        float r6 = fmaxf(fmaf(a[6], dv, b1.z), 0.f);
        float r7 = fmaxf(fmaf(a[7], dv, b1.w), 0.f);
        Xout[(size_t)vs * 8 + fl] = make_uint4(pack_bf16(r0, r1), pack_bf16(r2, r3),
                                               pack_bf16(r4, r5), pack_bf16(r6, r7));
    }
}

// ---------------- fused pool (block per graph, batch sorted) + linear + softmax ----------------
__device__ __forceinline__ int lbound(const int* a, int n, int key) {
    int lo = 0, hi = n;
    while (lo < hi) { int mid = (lo + hi) >> 1; if (a[mid] < key) lo = mid + 1; else hi = mid; }
    return lo;
}

__global__ __launch_bounds__(256) void pool_head(const unsigned* __restrict__ x1,
                                                 const unsigned* __restrict__ x2,
                                                 const unsigned* __restrict__ x3,
                                                 const int* __restrict__ batch,
                                                 const float* __restrict__ Wl,
                                                 const float* __restrict__ bl,
                                                 float* __restrict__ out, int n) {
    __shared__ int sb[2];
    __shared__ float red[4][64];
    __shared__ float ps[64];
    __shared__ float lg[10];
    int g = blockIdx.x, t = threadIdx.x;
    int wave = t >> 6, lane = t & 63;
    if (t < 2) sb[t] = lbound(batch, n, g + t);
    __syncthreads();
    int s0 = sb[0], s1 = sb[1];
    // packed loads: 2 nodes per wave per iter, each lane reads one uint (2 bf16)
    int half = lane >> 5, col = lane & 31;
    float a0 = 0.f, a1 = 0.f;
    for (int v = s0 + wave * 2 + half; v < s1; v += 8) {
        size_t off = (size_t)v * 32 + col;
        unsigned u1 = x1[off], u2 = x2[off], u3 = x3[off];
        a0 += (bf16_lo(u1) + bf16_lo(u2)) + bf16_lo(u3);
        a1 += (bf16_hi(u1) + bf16_hi(u2)) + bf16_hi(u3);
    }
    a0 += __shfl_xor(a0, 32, 64);
    a1 += __shfl_xor(a1, 32, 64);
    if (half == 0) { red[wave][2 * col] = a0; red[wave][2 * col + 1] = a1; }
    __syncthreads();
    if (t < 64) {
        int c = s1 - s0;
        float denom = 3.0f * (float)(c > 1 ? c : 1);
        ps[t] = (red[0][t] + red[1][t] + red[2][t] + red[3][t]) / denom;
    }
    __syncthreads();
    if (t < 10) {
        float a = bl[t];
        #pragma unroll 8
        for (int f = 0; f < 64; f++) a += ps[f] * Wl[f * 10 + t];
        lg[t] = a;
    }
    __syncthreads();
    if (t < 10) {
        float mx = -1e30f;
        for (int j = 0; j < 10; j++) mx = fmaxf(mx, lg[j]);
        float e = expf(lg[t] - mx);
        float ss = 0.f;
        for (int j = 0; j < 10; j++) ss += expf(lg[j] - mx);
        out[g * 10 + t] = e / ss;
    }
}

extern "C" void kernel_launch(void* const* d_in, const int* in_sizes, int n_in,
                              void* d_out, int out_size, void* d_ws, size_t ws_size,
                              hipStream_t stream) {
    const float* feats = (const float*)d_in[0];
    const int*   eidx  = (const int*)d_in[1];
    const int*   batch = (const int*)d_in[2];
    const float* W1 = (const float*)d_in[4];
    const float* b1 = (const float*)d_in[5];
    const float* W2 = (const float*)d_in[6];
    const float* b2 = (const float*)d_in[7];
    const float* W3 = (const float*)d_in[8];
    const float* b3 = (const float*)d_in[9];
    const float* Wl = (const float*)d_in[10];
    const float* bl = (const float*)d_in[11];
    float* out = (float*)d_out;

    int n = in_sizes[0] / 128;
    int E = in_sizes[1] / 2;
    int G = out_size / 10;
    int NB = ((n - 1) >> 9) + 1;                   // 512-node buckets
    int per = E / NB;
    int bcap = ALIGN_UP(per + per / 8 + 512, 64);  // mean + >15 sigma margin
    const int* row = eidx;       // destination
    const int* col = eidx + E;   // source

    char* ws = (char*)d_ws;
    size_t o = 0;
    size_t o_fill   = o; o += 2 * NBMAX * 4;                         // fillR | fillC (zeroed)
    size_t o_rowptr = o; o += ALIGN_UP((size_t)n * 4, 256);
    size_t o_indeg  = o; o += ALIGN_UP((size_t)n * 4, 256);
    size_t o_dinv   = o; o += ALIGN_UP((size_t)n * 4, 256);
    size_t o_csr    = o; o += ALIGN_UP((size_t)(E + 64) * 4, 256);   // +64 pad entries = n
    size_t o_z      = o; o += ALIGN_UP(((size_t)n + 1) * 64 * 2, 256); // bf16 Z (+dummy row n)
    size_t o_union  = o;                                             // RB+CB | x1..x3
    size_t rb_bytes = ALIGN_UP((size_t)NB * bcap * 4, 256);
    size_t xl_bytes = ALIGN_UP((size_t)n * 64 * 2, 256);             // bf16 x-layers
    (void)ws_size; (void)n_in;

    int*   fillR = (int*)(ws + o_fill);
    int*   fillC = fillR + NBMAX;
    int*   rowptr = (int*)(ws + o_rowptr);
    int*   indeg  = (int*)(ws + o_indeg);
    float* dinv   = (float*)(ws + o_dinv);
    int*   csr    = (int*)(ws + o_csr);
    unsigned* z   = (unsigned*)(ws + o_z);
    unsigned int*   RB = (unsigned int*)(ws + o_union);
    unsigned short* CB = (unsigned short*)(ws + o_union + rb_bytes);
    unsigned* x1 = (unsigned*)(ws + o_union);                        // overlays RB/CB
    unsigned* x2 = (unsigned*)(ws + o_union + xl_bytes);
    unsigned* x3 = (unsigned*)(ws + o_union + 2 * xl_bytes);

    hipMemsetAsync(ws + o_fill, 0, 2 * NBMAX * 4, stream);

    int gridG = n / 64 + 1;      // gemm: 64 nodes per block; always covers dummy row n
    int gridW = (n + 3) / 4;     // aggregate: one wave per node
    int gridB = (E + CHUNK - 1) / CHUNK;   // bin: chunk <= CHUNK edges/block

    bin_edges_sort<<<gridB, 1024, 0, stream>>>(row, col, E, NB, bcap, fillR, fillC, RB, CB);
    build_csr_impl<<<NB, 1024, 0, stream>>>(RB, CB, fillR, fillC,
                                            rowptr, indeg, dinv, csr, n, NB, E, bcap);

    // conv1 (RB/CB dead after build_csr; x1 overlays them)
    gemm_scale<128, false><<<gridG, 256, 0, stream>>>(feats, W1, dinv, z, n);
    aggregate<<<gridW, 256, 0, stream>>>((const uint4*)z, rowptr, indeg, csr, dinv, b1, (uint4*)x1, n);
    // conv2
    gemm_scale<64, true><<<gridG, 256, 0, stream>>>(x1, W2, dinv, z, n);
    aggregate<<<gridW, 256, 0, stream>>>((const uint4*)z, rowptr, indeg, csr, dinv, b2, (uint4*)x2, n);
    // conv3
    gemm_scale<64, true><<<gridG, 256, 0, stream>>>(x2, W3, dinv, z, n);
    aggregate<<<gridW, 256, 0, stream>>>((const uint4*)z, rowptr, indeg, csr, dinv, b3, (uint4*)x3, n);

    pool_head<<<G, 256, 0, stream>>>((const unsigned*)x1, (const unsigned*)x2,
                                     (const unsigned*)x3, batch, Wl, bl, out, n);
}